// Round 1
// baseline (1308.539 us; speedup 1.0000x reference)
//
#include <hip/hip_runtime.h>

// WaveRNN: 2D wave equation, T=512 sequential steps, B=4 batches of 160x160.
// One workgroup per batch; 32x32 threads each owning a 5x5 register patch.
// LDS used only for patch-edge halo exchange + probe staging + x broadcast.

#define NB 4
#define NT 512
#define NN 160
#define NP 32
#define C_DT 0.16f

#define TGY 32
#define TGX 32
#define PR 5
#define PC 5
#define EPITCH 161   // pad to break bank alignment on column-edge access

__global__ __launch_bounds__(1024, 1) void wave_kernel(
    const float* __restrict__ x,      // [B][T]
    const float* __restrict__ cmat,   // [N][N]
    const float* __restrict__ rho,    // [N][N]
    const int*   __restrict__ src_i_p,
    const int*   __restrict__ src_j_p,
    const int*   __restrict__ probe_i,// [P]
    const int*   __restrict__ probe_j,// [P]
    float*       __restrict__ y)      // [B][T][P]
{
    __shared__ float rowEdge[2*TGY+2][EPITCH]; // [0] and [65] are zero guards
    __shared__ float colEdge[2*TGX+2][EPITCH]; // indexed [edge][row]
    __shared__ float probeBuf[NP];
    __shared__ float xbuf[NT];

    const int b   = blockIdx.x;
    const int tid = threadIdx.x;
    const int ty  = tid >> 5;
    const int tx  = tid & 31;
    const int r0  = ty * PR;
    const int c0  = tx * PC;

    // ---- init: zero guard/edge arrays, stage x, load coeff, build masks ----
    {
        float* rz = &rowEdge[0][0];
        for (int i = tid; i < (2*TGY+2)*EPITCH; i += TGY*TGX) rz[i] = 0.0f;
        float* cz = &colEdge[0][0];
        for (int i = tid; i < (2*TGX+2)*EPITCH; i += TGY*TGX) cz[i] = 0.0f;
        for (int i = tid; i < NT; i += TGY*TGX) xbuf[i] = x[b*NT + i];
    }

    const int si = src_i_p[0];
    const int sj = src_j_p[0];

    float h1[PR][PC], h2[PR][PC], cf[PR][PC];
    unsigned pm[PR][PC];
    unsigned srcbits = 0;

    #pragma unroll
    for (int i = 0; i < PR; ++i) {
        #pragma unroll
        for (int j = 0; j < PC; ++j) {
            const int r = r0 + i, c = c0 + j;
            const float cc = cmat[r*NN + c];
            const float rr = rho[r*NN + c];
            cf[i][j] = C_DT * cc * cc / rr;
            h1[i][j] = 0.0f;
            h2[i][j] = 0.0f;
            unsigned m = 0;
            for (int p = 0; p < NP; ++p)
                if (probe_i[p] == r && probe_j[p] == c) m |= (1u << p);
            pm[i][j] = m;
            if (r == si && c == sj) srcbits |= (1u << (i*PC + j));
        }
    }

    __syncthreads();

    for (int t = 0; t < NT; ++t) {
        // ---- phase A: flush previous step's probes; read halos of h1 ----
        if (t > 0 && tid < NP)
            y[(size_t)b*NT*NP + (size_t)(t-1)*NP + tid] = probeBuf[tid];

        float nh[PC], sh[PC], wh[PR], eh[PR];
        #pragma unroll
        for (int j = 0; j < PC; ++j) {
            nh[j] = rowEdge[2*ty    ][c0+j];   // bottom row of ty-1 (or 0)
            sh[j] = rowEdge[2*ty + 3][c0+j];   // top row of ty+1 (or 0)
        }
        #pragma unroll
        for (int i = 0; i < PR; ++i) {
            wh[i] = colEdge[2*tx    ][r0+i];   // right col of tx-1 (or 0)
            eh[i] = colEdge[2*tx + 3][r0+i];   // left col of tx+1 (or 0)
        }
        const float xt = xbuf[t];

        // ---- phase B: stencil update (all in registers) ----
        float hn[PR][PC];
        #pragma unroll
        for (int i = 0; i < PR; ++i) {
            #pragma unroll
            for (int j = 0; j < PC; ++j) {
                const float up = (i == 0)    ? nh[j] : h1[i-1][j];
                const float dn = (i == PR-1) ? sh[j] : h1[i+1][j];
                const float lf = (j == 0)    ? wh[i] : h1[i][j-1];
                const float rt = (j == PC-1) ? eh[i] : h1[i][j+1];
                const float lap = up + dn + lf + rt - 4.0f * h1[i][j];
                hn[i][j] = 2.0f * h1[i][j] - h2[i][j] + cf[i][j] * lap;
            }
        }
        #pragma unroll
        for (int i = 0; i < PR; ++i) {
            #pragma unroll
            for (int j = 0; j < PC; ++j) {
                h2[i][j] = h1[i][j];
                float v = hn[i][j];
                if (srcbits & (1u << (i*PC + j))) v += xt;  // source injection
                h1[i][j] = v;
            }
        }

        __syncthreads();  // barrier1: all halo reads done before edges rewritten

        // ---- phase C: publish new edges + probe values ----
        #pragma unroll
        for (int j = 0; j < PC; ++j) {
            rowEdge[2*ty + 1][c0+j] = h1[0   ][j];
            rowEdge[2*ty + 2][c0+j] = h1[PR-1][j];
        }
        #pragma unroll
        for (int i = 0; i < PR; ++i) {
            colEdge[2*tx + 1][r0+i] = h1[i][0   ];
            colEdge[2*tx + 2][r0+i] = h1[i][PC-1];
        }
        #pragma unroll
        for (int i = 0; i < PR; ++i) {
            #pragma unroll
            for (int j = 0; j < PC; ++j) {
                unsigned m = pm[i][j];
                while (m) {
                    const int p = __ffs(m) - 1;
                    probeBuf[p] = h1[i][j];
                    m &= m - 1;
                }
            }
        }

        __syncthreads();  // barrier2: edges + probes visible for next step
    }

    if (tid < NP)
        y[(size_t)b*NT*NP + (size_t)(NT-1)*NP + tid] = probeBuf[tid];
}

extern "C" void kernel_launch(void* const* d_in, const int* in_sizes, int n_in,
                              void* d_out, int out_size, void* d_ws, size_t ws_size,
                              hipStream_t stream) {
    const float* x    = (const float*)d_in[0];
    const float* cmat = (const float*)d_in[1];
    const float* rho  = (const float*)d_in[2];
    const int*   si   = (const int*)d_in[3];
    const int*   sj   = (const int*)d_in[4];
    const int*   pi   = (const int*)d_in[5];
    const int*   pj   = (const int*)d_in[6];
    float*       y    = (float*)d_out;

    wave_kernel<<<NB, TGY*TGX, 0, stream>>>(x, cmat, rho, si, sj, pi, pj, y);
}

// Round 2
// 873.886 us; speedup vs baseline: 1.4974x; 1.4974x over previous
//
#include <hip/hip_runtime.h>

// WaveRNN: 2D wave equation, T=512 sequential steps, B=4 batches of 160x160.
// One workgroup per batch; 32x32 threads each owning a 5x5 register patch.
// Column halos via DPP wave shifts (same-wave lanes); row halos via LDS edges.
// Time loop unrolled x2 with A/B register-array swap (no h2<-h1 copies).

#define NB 4
#define NT 512
#define NN 160
#define NP 32
#define C_DT 0.16f

#define TGY 32
#define TGX 32
#define PR 5
#define PC 5
#define EPITCH 161
#define K_ENT 6

#if defined(__has_builtin)
#if __has_builtin(__builtin_amdgcn_update_dpp)
#define HAVE_DPP 1
#endif
#endif

__device__ __forceinline__ float shr1(float v) {   // lane i <- lane i-1
#ifdef HAVE_DPP
    return __int_as_float(__builtin_amdgcn_update_dpp(
        0, __float_as_int(v), 0x138 /*wave_shr:1*/, 0xf, 0xf, true));
#else
    return __shfl_up(v, 1, 64);
#endif
}
__device__ __forceinline__ float shl1(float v) {   // lane i <- lane i+1
#ifdef HAVE_DPP
    return __int_as_float(__builtin_amdgcn_update_dpp(
        0, __float_as_int(v), 0x130 /*wave_shl:1*/, 0xf, 0xf, true));
#else
    return __shfl_down(v, 1, 64);
#endif
}

__global__ __launch_bounds__(1024, 1) void wave_kernel(
    const float* __restrict__ x,      // [B][T]
    const float* __restrict__ cmat,   // [N][N]
    const float* __restrict__ rho,    // [N][N]
    const int*   __restrict__ src_i_p,
    const int*   __restrict__ src_j_p,
    const int*   __restrict__ probe_i,// [P]
    const int*   __restrict__ probe_j,// [P]
    float*       __restrict__ y)      // [B][T][P]
{
    __shared__ float rowEdge[2*TGY+2][EPITCH]; // rows 0 and 65 are zero guards
    __shared__ float probeBuf[NP];
    __shared__ float xbuf[NT];
    __shared__ int   pco[2*NP];

    const int b   = blockIdx.x;
    const int tid = threadIdx.x;
    const int ty  = tid >> 5;
    const int tx  = tid & 31;
    const int r0  = ty * PR;
    const int c0  = tx * PC;

    // ---- init ----
    {
        float* rz = &rowEdge[0][0];
        for (int i = tid; i < (2*TGY+2)*EPITCH; i += TGY*TGX) rz[i] = 0.0f;
        for (int i = tid; i < NT; i += TGY*TGX) xbuf[i] = x[b*NT + i];
        if (tid < NP) { pco[tid] = probe_i[tid]; pco[NP + tid] = probe_j[tid]; }
    }

    const int si = src_i_p[0];
    const int sj = src_j_p[0];

    float hA[PR][PC], hB[PR][PC], cf[PR][PC];
    #pragma unroll
    for (int i = 0; i < PR; ++i)
        #pragma unroll
        for (int j = 0; j < PC; ++j) {
            const int r = r0 + i, c = c0 + j;
            const float cc = cmat[r*NN + c];
            const float rr = rho[r*NN + c];
            cf[i][j] = C_DT * cc * cc / rr;
            hA[i][j] = 0.0f;
            hB[i][j] = 0.0f;
        }

    unsigned srcMask = 0;
    if (r0 <= si && si < r0 + PR && c0 <= sj && sj < c0 + PC)
        srcMask = 1u << ((si - r0)*PC + (sj - c0));

    __syncthreads();

    // packed probe ownership: up to K_ENT entries of (p:5 bits | cell:5 bits)<<10k
    unsigned long long ent = 0;
    int ecnt = 0;
    for (int p = 0; p < NP; ++p) {
        const int r = pco[p], c = pco[NP + p];
        if (r >= r0 && r < r0 + PR && c >= c0 && c < c0 + PC) {
            const int ij = (r - r0)*PC + (c - c0);
            if (ecnt < K_ENT)
                ent |= ((unsigned long long)(unsigned)(p | (ij << 5))) << (10*ecnt);
            ecnt++;
        }
    }

    // loop-invariant LDS addresses
    float* const rowN = &rowEdge[2*ty    ][c0];  // north halo (bottom of ty-1)
    float* const rowS = &rowEdge[2*ty + 3][c0];  // south halo (top of ty+1)
    float* const rowT = &rowEdge[2*ty + 1][c0];  // publish: my top row
    float* const rowB = &rowEdge[2*ty + 2][c0];  // publish: my bottom row
    float* const yb   = y + (size_t)b*NT*NP;

#define STEP(HS, HD, TT)                                                       \
    {                                                                          \
        const int tt = (TT);                                                   \
        if (tt > 0 && tid < NP) yb[(size_t)(tt-1)*NP + tid] = probeBuf[tid];   \
        float nh[PC], sh[PC], wh[PR], eh[PR];                                  \
        _Pragma("unroll")                                                      \
        for (int j = 0; j < PC; ++j) { nh[j] = rowN[j]; sh[j] = rowS[j]; }     \
        _Pragma("unroll")                                                      \
        for (int i = 0; i < PR; ++i) {                                         \
            const float tw = shr1(HS[i][PC-1]);                                \
            wh[i] = (tx == 0) ? 0.0f : tw;                                     \
            const float te = shl1(HS[i][0]);                                   \
            eh[i] = (tx == TGX-1) ? 0.0f : te;                                 \
        }                                                                      \
        _Pragma("unroll")                                                      \
        for (int i = 0; i < PR; ++i) {                                         \
            _Pragma("unroll")                                                  \
            for (int j = 0; j < PC; ++j) {                                     \
                const float up = (i == 0)    ? nh[j] : HS[i-1][j];             \
                const float dn = (i == PR-1) ? sh[j] : HS[i+1][j];             \
                const float lf = (j == 0)    ? wh[i] : HS[i][j-1];             \
                const float rt = (j == PC-1) ? eh[i] : HS[i][j+1];             \
                const float s   = (up + dn) + (lf + rt);                       \
                const float lap = __builtin_fmaf(-4.0f, HS[i][j], s);          \
                const float t1  = __builtin_fmaf(2.0f, HS[i][j], -HD[i][j]);   \
                HD[i][j] = __builtin_fmaf(cf[i][j], lap, t1);                  \
            }                                                                  \
        }                                                                      \
        if (srcMask) {                                                         \
            const float xt = xbuf[tt];                                         \
            _Pragma("unroll")                                                  \
            for (int i = 0; i < PR; ++i)                                       \
                _Pragma("unroll")                                              \
                for (int j = 0; j < PC; ++j)                                   \
                    if (srcMask & (1u << (i*PC + j))) HD[i][j] += xt;          \
        }                                                                      \
        __syncthreads();  /* halo+probe reads done; safe to rewrite edges */   \
        _Pragma("unroll")                                                      \
        for (int j = 0; j < PC; ++j) {                                         \
            rowT[j] = HD[0][j];                                                \
            rowB[j] = HD[PR-1][j];                                             \
        }                                                                      \
        if (ecnt) {                                                            \
            _Pragma("unroll")                                                  \
            for (int k = 0; k < K_ENT; ++k) {                                  \
                if (k < ecnt) {                                                \
                    const int e  = (int)((ent >> (10*k)) & 0x3FF);             \
                    const int p  = e & 31;                                     \
                    const int ij = e >> 5;                                     \
                    float v = 0.0f;                                            \
                    _Pragma("unroll")                                          \
                    for (int i = 0; i < PR; ++i)                               \
                        _Pragma("unroll")                                      \
                        for (int j = 0; j < PC; ++j)                           \
                            if (ij == i*PC + j) v = HD[i][j];                  \
                    probeBuf[p] = v;                                           \
                }                                                              \
            }                                                                  \
        }                                                                      \
        __syncthreads();  /* edges + probes visible for next step */           \
    }

    for (int t = 0; t < NT; t += 2) {
        STEP(hA, hB, t);
        STEP(hB, hA, t + 1);
    }

    if (tid < NP) yb[(size_t)(NT-1)*NP + tid] = probeBuf[tid];
#undef STEP
}

extern "C" void kernel_launch(void* const* d_in, const int* in_sizes, int n_in,
                              void* d_out, int out_size, void* d_ws, size_t ws_size,
                              hipStream_t stream) {
    const float* x    = (const float*)d_in[0];
    const float* cmat = (const float*)d_in[1];
    const float* rho  = (const float*)d_in[2];
    const int*   si   = (const int*)d_in[3];
    const int*   sj   = (const int*)d_in[4];
    const int*   pi   = (const int*)d_in[5];
    const int*   pj   = (const int*)d_in[6];
    float*       y    = (float*)d_out;

    wave_kernel<<<NB, TGY*TGX, 0, stream>>>(x, cmat, rho, si, sj, pi, pj, y);
}